// Round 2
// baseline (4239.478 us; speedup 1.0000x reference)
//
#include <hip/hip_runtime.h>
#include <hip/hip_fp16.h>

#define NN 50000
#define NE 200000
#define IND 512
#define HIDD 2000
#define LATD 128

typedef _Float16 f16x8 __attribute__((ext_vector_type(8)));
typedef float f32x4 __attribute__((ext_vector_type(4)));

// ---- degree: deg[col[e]] += 1 ----
__global__ void k_degree(const int* __restrict__ col, float* __restrict__ deg) {
    int e = blockIdx.x * 256 + threadIdx.x;
    if (e < NE) atomicAdd(&deg[col[e]], 1.0f);
}

// ---- dis = rsqrt(deg + 1 self-loop) ----
__global__ void k_dis(const float* __restrict__ deg, float* __restrict__ dis) {
    int i = blockIdx.x * 256 + threadIdx.x;
    if (i < NN) dis[i] = rsqrtf(deg[i] + 1.0f);
}

// ---- f32 [R][C] -> fp16 [C][R] transpose+convert ----
__global__ void k_transpose_cvt(const float* __restrict__ in,
                                _Float16* __restrict__ out, int R, int C) {
    int idx = blockIdx.x * 256 + threadIdx.x;
    if (idx < R * C) {
        int r = idx / C, c = idx - r * C;
        out[c * R + r] = (_Float16)in[idx];
    }
}

// ---- scatter x (f32) into aggx (f32): 1 wave per virtual edge, 512 dims ----
__global__ void k_scatter_x(const float* __restrict__ x, const int* __restrict__ ei,
                            const float* __restrict__ dis, float* __restrict__ aggx) {
    int ve = blockIdx.x * 4 + (threadIdx.x >> 6);
    if (ve >= NE + NN) return;
    int lane = threadIdx.x & 63;
    int r, c; float norm;
    if (ve < NE) { r = ei[ve]; c = ei[NE + ve]; norm = dis[r] * dis[c]; }
    else         { r = ve - NE; c = r; float d = dis[r]; norm = d * d; }
    const float* xr = x + (size_t)r * IND + lane * 8;
    float* ar = aggx + (size_t)c * IND + lane * 8;
    float4 v0 = *(const float4*)xr;
    float4 v1 = *(const float4*)(xr + 4);
    atomicAdd(ar + 0, v0.x * norm); atomicAdd(ar + 1, v0.y * norm);
    atomicAdd(ar + 2, v0.z * norm); atomicAdd(ar + 3, v0.w * norm);
    atomicAdd(ar + 4, v1.x * norm); atomicAdd(ar + 5, v1.y * norm);
    atomicAdd(ar + 6, v1.z * norm); atomicAdd(ar + 7, v1.w * norm);
}

// ---- f32 -> fp16 convert (8 elems/thread) ----
__global__ void k_f2h(const float* __restrict__ in, _Float16* __restrict__ out, int n8) {
    int i = blockIdx.x * 256 + threadIdx.x;
    if (i < n8) {
        float4 a = ((const float4*)in)[i * 2];
        float4 b = ((const float4*)in)[i * 2 + 1];
        f16x8 o;
        o[0] = (_Float16)a.x; o[1] = (_Float16)a.y; o[2] = (_Float16)a.z; o[3] = (_Float16)a.w;
        o[4] = (_Float16)b.x; o[5] = (_Float16)b.y; o[6] = (_Float16)b.z; o[7] = (_Float16)b.w;
        ((f16x8*)out)[i] = o;
    }
}

// ---- MFMA GEMM, C[M][N] = A[M][K] @ Bt[N][K]^T, fp16 in, f32 acc ----
// 128x128 tile, 4 waves of 64x64 each. RELU_BIAS: +bias, ReLU, fp16 out; else f32 out.
template<bool RELU_BIAS>
__global__ __launch_bounds__(256, 2) void k_gemm_bt(
    const _Float16* __restrict__ A,
    const _Float16* __restrict__ Bt,
    const float* __restrict__ bias,
    _Float16* __restrict__ Ch,   // fp16 out if RELU_BIAS
    float* __restrict__ Cf,      // f32 out otherwise
    int M, int N, int K)
{
    __shared__ _Float16 As[128 * 40];  // row stride 40 elems = 80B (2-way banks: free)
    __shared__ _Float16 Bs[128 * 40];

    const int tid = threadIdx.x;
    const int mBase = blockIdx.x * 128;
    const int nBase = blockIdx.y * 128;
    const int lane = tid & 63;
    const int w = tid >> 6;
    const int wm = (w >> 1) * 64;
    const int wn = (w & 1) * 64;
    const int lm = lane & 15;
    const int quad = lane >> 4;

    f32x4 acc[4][4];
    #pragma unroll
    for (int i = 0; i < 4; ++i)
        #pragma unroll
        for (int j = 0; j < 4; ++j)
            acc[i][j] = (f32x4){0.f, 0.f, 0.f, 0.f};

    for (int k0 = 0; k0 < K; k0 += 32) {
        __syncthreads();
        #pragma unroll
        for (int p = 0; p < 2; ++p) {
            int id = p * 256 + tid;      // 0..511
            int row = id >> 2;           // 0..127
            int cv = (id & 3) * 8;       // 0,8,16,24
            uint4 qa = make_uint4(0u, 0u, 0u, 0u);
            int gr = mBase + row;
            if (gr < M && (k0 + cv) < K)
                qa = *(const uint4*)(A + (size_t)gr * K + k0 + cv);
            *(uint4*)&As[row * 40 + cv] = qa;
            uint4 qb = make_uint4(0u, 0u, 0u, 0u);
            int gn = nBase + row;
            if (gn < N && (k0 + cv) < K)
                qb = *(const uint4*)(Bt + (size_t)gn * K + k0 + cv);
            *(uint4*)&Bs[row * 40 + cv] = qb;
        }
        __syncthreads();

        f16x8 af[4], bfr[4];
        #pragma unroll
        for (int mi = 0; mi < 4; ++mi)
            af[mi] = *(const f16x8*)&As[(wm + mi * 16 + lm) * 40 + quad * 8];
        #pragma unroll
        for (int ni = 0; ni < 4; ++ni)
            bfr[ni] = *(const f16x8*)&Bs[(wn + ni * 16 + lm) * 40 + quad * 8];
        #pragma unroll
        for (int mi = 0; mi < 4; ++mi)
            #pragma unroll
            for (int ni = 0; ni < 4; ++ni)
                acc[mi][ni] = __builtin_amdgcn_mfma_f32_16x16x32_f16(
                    af[mi], bfr[ni], acc[mi][ni], 0, 0, 0);
    }

    // epilogue; C/D layout: col = lane&15, row = quad*4 + reg  [verified m89/m91]
    #pragma unroll
    for (int mi = 0; mi < 4; ++mi) {
        #pragma unroll
        for (int ni = 0; ni < 4; ++ni) {
            int col = nBase + wn + ni * 16 + lm;
            if (col >= N) continue;
            float bval = RELU_BIAS ? bias[col] : 0.f;
            #pragma unroll
            for (int r = 0; r < 4; ++r) {
                int rowg = mBase + wm + mi * 16 + quad * 4 + r;
                if (rowg >= M) continue;
                float v = acc[mi][ni][r];
                if (RELU_BIAS) {
                    v = fmaxf(v + bval, 0.f);
                    Ch[(size_t)rowg * N + col] = (_Float16)v;
                } else {
                    Cf[(size_t)rowg * N + col] = v;
                }
            }
        }
    }
}

// ---- scatter t (f32, 128 dims) into out accumulator: 1 wave/virtual edge ----
__global__ void k_scatter_t(const float* __restrict__ t, const int* __restrict__ ei,
                            const float* __restrict__ dis, float* __restrict__ oacc) {
    int ve = blockIdx.x * 4 + (threadIdx.x >> 6);
    if (ve >= NE + NN) return;
    int lane = threadIdx.x & 63;
    int r, c; float norm;
    if (ve < NE) { r = ei[ve]; c = ei[NE + ve]; norm = dis[r] * dis[c]; }
    else         { r = ve - NE; c = r; float d = dis[r]; norm = d * d; }
    float2 tv = *(const float2*)(t + (size_t)r * LATD + lane * 2);
    float* op = oacc + (size_t)c * LATD + lane * 2;
    atomicAdd(op,     tv.x * norm);
    atomicAdd(op + 1, tv.y * norm);
}

// ---- out = sigmoid(oacc + b2), f32 ----
__global__ void k_sigmoid(const float* __restrict__ acc, const float* __restrict__ b2,
                          float* __restrict__ out) {
    int i = blockIdx.x * 256 + threadIdx.x;
    if (i < NN * LATD) {
        float v = acc[i] + b2[i & (LATD - 1)];
        out[i] = 1.0f / (1.0f + __expf(-v));
    }
}

extern "C" void kernel_launch(void* const* d_in, const int* in_sizes, int n_in,
                              void* d_out, int out_size, void* d_ws, size_t ws_size,
                              hipStream_t stream) {
    const float* x  = (const float*)d_in[0];
    const int* ei   = (const int*)d_in[1];
    const float* W1 = (const float*)d_in[2];
    const float* b1 = (const float*)d_in[3];
    const float* W2 = (const float*)d_in[4];
    const float* b2 = (const float*)d_in[5];
    float* out = (float*)d_out;

    char* p = (char*)d_ws;
    auto alloc = [&](size_t bytes) {
        char* q = p; p += (bytes + 255) & ~(size_t)255; return q;
    };
    float* deg      = (float*)alloc((size_t)NN * 4);
    float* dis      = (float*)alloc((size_t)NN * 4);
    _Float16* W1T   = (_Float16*)alloc((size_t)HIDD * IND * 2);
    _Float16* W2T   = (_Float16*)alloc((size_t)LATD * HIDD * 2);
    _Float16* Ah    = (_Float16*)alloc((size_t)NN * IND * 2);   // fp16 aggregated x
    _Float16* h     = (_Float16*)alloc((size_t)NN * HIDD * 2);  // fp16 hidden
    float* big      = (float*)alloc((size_t)NN * IND * 4);      // aliased f32 region
    float* aggx = big;                     // [NN*IND], live until k_f2h
    float* t    = big;                     // [NN*LATD], live after GEMM1
    float* oacc = big + (size_t)NN * LATD; // [NN*LATD]

    hipMemsetAsync(deg,  0, (size_t)NN * 4, stream);
    hipMemsetAsync(aggx, 0, (size_t)NN * IND * 4, stream);

    k_degree<<<(NE + 255) / 256, 256, 0, stream>>>(ei + NE, deg);
    k_dis<<<(NN + 255) / 256, 256, 0, stream>>>(deg, dis);
    k_transpose_cvt<<<(IND * HIDD + 255) / 256, 256, 0, stream>>>(W1, W1T, IND, HIDD);
    k_transpose_cvt<<<(HIDD * LATD + 255) / 256, 256, 0, stream>>>(W2, W2T, HIDD, LATD);
    k_scatter_x<<<(NE + NN + 3) / 4, 256, 0, stream>>>(x, ei, dis, aggx);
    k_f2h<<<(NN * IND / 8 + 255) / 256, 256, 0, stream>>>(aggx, Ah, NN * IND / 8);

    hipMemsetAsync(oacc, 0, (size_t)NN * LATD * 4, stream);  // after aggx is dead

    dim3 g1((NN + 127) / 128, (HIDD + 127) / 128);
    k_gemm_bt<true><<<g1, 256, 0, stream>>>(Ah, W1T, b1, h, nullptr, NN, HIDD, IND);
    dim3 g2((NN + 127) / 128, (LATD + 127) / 128);
    k_gemm_bt<false><<<g2, 256, 0, stream>>>(h, W2T, nullptr, nullptr, t, NN, LATD, HIDD);

    k_scatter_t<<<(NE + NN + 3) / 4, 256, 0, stream>>>(t, ei, dis, oacc);
    k_sigmoid<<<(NN * LATD + 255) / 256, 256, 0, stream>>>(oacc, b2, out);
}

// Round 3
// 779.984 us; speedup vs baseline: 5.4353x; 5.4353x over previous
//
#include <hip/hip_runtime.h>
#include <hip/hip_fp16.h>

#define NN 50000
#define NE 200000
#define IND 512
#define HIDD 2000
#define LATD 128

typedef _Float16 f16x8 __attribute__((ext_vector_type(8)));
typedef float f32x4 __attribute__((ext_vector_type(4)));

// ---- in-degree (int): deg[col[e]] += 1 ----
__global__ void k_degree(const int* __restrict__ col, int* __restrict__ deg) {
    int e = blockIdx.x * 256 + threadIdx.x;
    if (e < NE) atomicAdd(&deg[col[e]], 1);
}

// ---- dis = rsqrt(deg + 1 self-loop) ----
__global__ void k_dis(const int* __restrict__ deg, float* __restrict__ dis) {
    int i = blockIdx.x * 256 + threadIdx.x;
    if (i < NN) dis[i] = rsqrtf((float)deg[i] + 1.0f);
}

// ---- exclusive prefix scan of deg -> row_ptr (single 1024-thread block) ----
__global__ void k_scan(const int* __restrict__ deg, int* __restrict__ row_ptr) {
    __shared__ int smem[1024];
    const int tid = threadIdx.x;
    int carry = 0;
    for (int chunk = 0; chunk < NN; chunk += 1024) {
        int i = chunk + tid;
        int v = (i < NN) ? deg[i] : 0;
        smem[tid] = v;
        __syncthreads();
        #pragma unroll
        for (int off = 1; off < 1024; off <<= 1) {
            int t = (tid >= off) ? smem[tid - off] : 0;
            __syncthreads();
            if (tid >= off) smem[tid] += t;
            __syncthreads();
        }
        if (i < NN) row_ptr[i] = carry + smem[tid] - v;   // exclusive
        int tot = smem[1023];
        __syncthreads();
        carry += tot;
    }
    if (tid == 0) row_ptr[NN] = carry;
}

// ---- fill CSR: csr_src[row_ptr[c] + cursor[c]++] = r ----
__global__ void k_fill(const int* __restrict__ ei, const int* __restrict__ row_ptr,
                       int* __restrict__ cursor, int* __restrict__ csr_src) {
    int e = blockIdx.x * 256 + threadIdx.x;
    if (e < NE) {
        int r = ei[e], c = ei[NE + e];
        int pos = atomicAdd(&cursor[c], 1);
        csr_src[row_ptr[c] + pos] = r;
    }
}

// ---- f32 [R][C] -> fp16 [C][R] transpose+convert ----
__global__ void k_transpose_cvt(const float* __restrict__ in,
                                _Float16* __restrict__ out, int R, int C) {
    int idx = blockIdx.x * 256 + threadIdx.x;
    if (idx < R * C) {
        int r = idx / C, c = idx - r * C;
        out[c * R + r] = (_Float16)in[idx];
    }
}

// ---- gather-aggregate x: Ah[dst] = fp16( dd*(sum_in dis[s]*x[s] + dd*x[dst]) ) ----
// one wave per dst node, 8 f32 dims per lane
__global__ void k_gather_x(const float* __restrict__ x, const int* __restrict__ row_ptr,
                           const int* __restrict__ csr_src, const float* __restrict__ dis,
                           _Float16* __restrict__ Ah) {
    int dst = blockIdx.x * 4 + (threadIdx.x >> 6);
    if (dst >= NN) return;
    int lane = threadIdx.x & 63;
    float dd = dis[dst];
    const float* xd = x + (size_t)dst * IND + lane * 8;
    float4 a0 = *(const float4*)xd;
    float4 a1 = *(const float4*)(xd + 4);
    float acc[8] = { dd*a0.x, dd*a0.y, dd*a0.z, dd*a0.w,
                     dd*a1.x, dd*a1.y, dd*a1.z, dd*a1.w };
    int beg = row_ptr[dst], end = row_ptr[dst + 1];
    for (int i = beg; i < end; ++i) {
        int s = csr_src[i];
        float ns = dis[s];
        const float* xs = x + (size_t)s * IND + lane * 8;
        float4 b0 = *(const float4*)xs;
        float4 b1 = *(const float4*)(xs + 4);
        acc[0] += ns * b0.x; acc[1] += ns * b0.y; acc[2] += ns * b0.z; acc[3] += ns * b0.w;
        acc[4] += ns * b1.x; acc[5] += ns * b1.y; acc[6] += ns * b1.z; acc[7] += ns * b1.w;
    }
    f16x8 o;
    #pragma unroll
    for (int i = 0; i < 8; ++i) o[i] = (_Float16)(dd * acc[i]);
    *(f16x8*)(Ah + (size_t)dst * IND + lane * 8) = o;
}

// ---- gather-aggregate t + bias + sigmoid -> out (f32) ----
// one wave per dst node, 2 f32 dims per lane
__global__ void k_gather_t(const float* __restrict__ t, const int* __restrict__ row_ptr,
                           const int* __restrict__ csr_src, const float* __restrict__ dis,
                           const float* __restrict__ b2, float* __restrict__ out) {
    int dst = blockIdx.x * 4 + (threadIdx.x >> 6);
    if (dst >= NN) return;
    int lane = threadIdx.x & 63;
    float dd = dis[dst];
    float2 td = *(const float2*)(t + (size_t)dst * LATD + lane * 2);
    float accx = dd * td.x, accy = dd * td.y;
    int beg = row_ptr[dst], end = row_ptr[dst + 1];
    for (int i = beg; i < end; ++i) {
        int s = csr_src[i];
        float ns = dis[s];
        float2 ts = *(const float2*)(t + (size_t)s * LATD + lane * 2);
        accx += ns * ts.x; accy += ns * ts.y;
    }
    float2 bb = *(const float2*)(b2 + lane * 2);
    float vx = dd * accx + bb.x;
    float vy = dd * accy + bb.y;
    float2 o;
    o.x = 1.0f / (1.0f + __expf(-vx));
    o.y = 1.0f / (1.0f + __expf(-vy));
    *(float2*)(out + (size_t)dst * LATD + lane * 2) = o;
}

// ---- MFMA GEMM, C[M][N] = A[M][K] @ Bt[N][K]^T, fp16 in, f32 acc ----
template<bool RELU_BIAS>
__global__ __launch_bounds__(256, 2) void k_gemm_bt(
    const _Float16* __restrict__ A,
    const _Float16* __restrict__ Bt,
    const float* __restrict__ bias,
    _Float16* __restrict__ Ch,
    float* __restrict__ Cf,
    int M, int N, int K)
{
    __shared__ _Float16 As[128 * 40];
    __shared__ _Float16 Bs[128 * 40];

    const int tid = threadIdx.x;
    const int mBase = blockIdx.x * 128;
    const int nBase = blockIdx.y * 128;
    const int lane = tid & 63;
    const int w = tid >> 6;
    const int wm = (w >> 1) * 64;
    const int wn = (w & 1) * 64;
    const int lm = lane & 15;
    const int quad = lane >> 4;

    f32x4 acc[4][4];
    #pragma unroll
    for (int i = 0; i < 4; ++i)
        #pragma unroll
        for (int j = 0; j < 4; ++j)
            acc[i][j] = (f32x4){0.f, 0.f, 0.f, 0.f};

    for (int k0 = 0; k0 < K; k0 += 32) {
        __syncthreads();
        #pragma unroll
        for (int p = 0; p < 2; ++p) {
            int id = p * 256 + tid;
            int row = id >> 2;
            int cv = (id & 3) * 8;
            uint4 qa = make_uint4(0u, 0u, 0u, 0u);
            int gr = mBase + row;
            if (gr < M && (k0 + cv) < K)
                qa = *(const uint4*)(A + (size_t)gr * K + k0 + cv);
            *(uint4*)&As[row * 40 + cv] = qa;
            uint4 qb = make_uint4(0u, 0u, 0u, 0u);
            int gn = nBase + row;
            if (gn < N && (k0 + cv) < K)
                qb = *(const uint4*)(Bt + (size_t)gn * K + k0 + cv);
            *(uint4*)&Bs[row * 40 + cv] = qb;
        }
        __syncthreads();

        f16x8 af[4], bfr[4];
        #pragma unroll
        for (int mi = 0; mi < 4; ++mi)
            af[mi] = *(const f16x8*)&As[(wm + mi * 16 + lm) * 40 + quad * 8];
        #pragma unroll
        for (int ni = 0; ni < 4; ++ni)
            bfr[ni] = *(const f16x8*)&Bs[(wn + ni * 16 + lm) * 40 + quad * 8];
        #pragma unroll
        for (int mi = 0; mi < 4; ++mi)
            #pragma unroll
            for (int ni = 0; ni < 4; ++ni)
                acc[mi][ni] = __builtin_amdgcn_mfma_f32_16x16x32_f16(
                    af[mi], bfr[ni], acc[mi][ni], 0, 0, 0);
    }

    #pragma unroll
    for (int mi = 0; mi < 4; ++mi) {
        #pragma unroll
        for (int ni = 0; ni < 4; ++ni) {
            int col = nBase + wn + ni * 16 + lm;
            if (col >= N) continue;
            float bval = RELU_BIAS ? bias[col] : 0.f;
            #pragma unroll
            for (int r = 0; r < 4; ++r) {
                int rowg = mBase + wm + mi * 16 + quad * 4 + r;
                if (rowg >= M) continue;
                float v = acc[mi][ni][r];
                if (RELU_BIAS) {
                    v = fmaxf(v + bval, 0.f);
                    Ch[(size_t)rowg * N + col] = (_Float16)v;
                } else {
                    Cf[(size_t)rowg * N + col] = v;
                }
            }
        }
    }
}

extern "C" void kernel_launch(void* const* d_in, const int* in_sizes, int n_in,
                              void* d_out, int out_size, void* d_ws, size_t ws_size,
                              hipStream_t stream) {
    const float* x  = (const float*)d_in[0];
    const int* ei   = (const int*)d_in[1];
    const float* W1 = (const float*)d_in[2];
    const float* b1 = (const float*)d_in[3];
    const float* W2 = (const float*)d_in[4];
    const float* b2 = (const float*)d_in[5];
    float* out = (float*)d_out;

    char* p = (char*)d_ws;
    auto alloc = [&](size_t bytes) {
        char* q = p; p += (bytes + 255) & ~(size_t)255; return q;
    };
    int* deg        = (int*)alloc((size_t)NN * 4);
    int* row_ptr    = (int*)alloc((size_t)(NN + 1) * 4);
    int* cursor     = (int*)alloc((size_t)NN * 4);
    int* csr_src    = (int*)alloc((size_t)NE * 4);
    float* dis      = (float*)alloc((size_t)NN * 4);
    _Float16* W1T   = (_Float16*)alloc((size_t)HIDD * IND * 2);
    _Float16* W2T   = (_Float16*)alloc((size_t)LATD * HIDD * 2);
    _Float16* Ah    = (_Float16*)alloc((size_t)NN * IND * 2);
    _Float16* h     = (_Float16*)alloc((size_t)NN * HIDD * 2);
    float* t        = (float*)alloc((size_t)NN * LATD * 4);

    hipMemsetAsync(deg,    0, (size_t)NN * 4, stream);
    hipMemsetAsync(cursor, 0, (size_t)NN * 4, stream);

    k_degree<<<(NE + 255) / 256, 256, 0, stream>>>(ei + NE, deg);
    k_dis<<<(NN + 255) / 256, 256, 0, stream>>>(deg, dis);
    k_scan<<<1, 1024, 0, stream>>>(deg, row_ptr);
    k_fill<<<(NE + 255) / 256, 256, 0, stream>>>(ei, row_ptr, cursor, csr_src);

    k_transpose_cvt<<<(IND * HIDD + 255) / 256, 256, 0, stream>>>(W1, W1T, IND, HIDD);
    k_transpose_cvt<<<(HIDD * LATD + 255) / 256, 256, 0, stream>>>(W2, W2T, HIDD, LATD);

    k_gather_x<<<(NN + 3) / 4, 256, 0, stream>>>(x, row_ptr, csr_src, dis, Ah);

    dim3 g1((NN + 127) / 128, (HIDD + 127) / 128);
    k_gemm_bt<true><<<g1, 256, 0, stream>>>(Ah, W1T, b1, h, nullptr, NN, HIDD, IND);
    dim3 g2((NN + 127) / 128, (LATD + 127) / 128);
    k_gemm_bt<false><<<g2, 256, 0, stream>>>(h, W2T, nullptr, nullptr, t, NN, LATD, HIDD);

    k_gather_t<<<(NN + 3) / 4, 256, 0, stream>>>(t, row_ptr, csr_src, dis, b2, out);
}

// Round 4
// 620.758 us; speedup vs baseline: 6.8295x; 1.2565x over previous
//
#include <hip/hip_runtime.h>
#include <hip/hip_fp16.h>

#define NN 50000
#define NE 200000
#define IND 512
#define HIDD 2000
#define LATD 128

#define M_PAD 50048    // 391 * 128
#define N1_PAD 2048    // HIDD padded to tile multiple (pad cols forced to exact 0)

typedef _Float16 f16x8 __attribute__((ext_vector_type(8)));
typedef float f32x4 __attribute__((ext_vector_type(4)));

__device__ __forceinline__ void gload_lds16(const _Float16* g, _Float16* l) {
    __builtin_amdgcn_global_load_lds(
        (const __attribute__((address_space(1))) unsigned int*)g,
        (__attribute__((address_space(3))) unsigned int*)l,
        16, 0, 0);
}

// ---- in-degree (int): deg[col[e]] += 1 ----
__global__ void k_degree(const int* __restrict__ col, int* __restrict__ deg) {
    int e = blockIdx.x * 256 + threadIdx.x;
    if (e < NE) atomicAdd(&deg[col[e]], 1);
}

// ---- dis = rsqrt(deg + 1 self-loop) ----
__global__ void k_dis(const int* __restrict__ deg, float* __restrict__ dis) {
    int i = blockIdx.x * 256 + threadIdx.x;
    if (i < NN) dis[i] = rsqrtf((float)deg[i] + 1.0f);
}

// ---- exclusive prefix scan of deg -> row_ptr (single 1024-thread block) ----
__global__ void k_scan(const int* __restrict__ deg, int* __restrict__ row_ptr) {
    __shared__ int smem[1024];
    const int tid = threadIdx.x;
    int carry = 0;
    for (int chunk = 0; chunk < NN; chunk += 1024) {
        int i = chunk + tid;
        int v = (i < NN) ? deg[i] : 0;
        smem[tid] = v;
        __syncthreads();
        #pragma unroll
        for (int off = 1; off < 1024; off <<= 1) {
            int t = (tid >= off) ? smem[tid - off] : 0;
            __syncthreads();
            if (tid >= off) smem[tid] += t;
            __syncthreads();
        }
        if (i < NN) row_ptr[i] = carry + smem[tid] - v;   // exclusive
        int tot = smem[1023];
        __syncthreads();
        carry += tot;
    }
    if (tid == 0) row_ptr[NN] = carry;
}

// ---- fill CSR: csr_src[row_ptr[c] + cursor[c]++] = r ----
__global__ void k_fill(const int* __restrict__ ei, const int* __restrict__ row_ptr,
                       int* __restrict__ cursor, int* __restrict__ csr_src) {
    int e = blockIdx.x * 256 + threadIdx.x;
    if (e < NE) {
        int r = ei[e], c = ei[NE + e];
        int pos = atomicAdd(&cursor[c], 1);
        csr_src[row_ptr[c] + pos] = r;
    }
}

// ---- f32 [R][C] -> fp16 out[c*ldo + r] transpose+convert ----
__global__ void k_transpose_cvt(const float* __restrict__ in,
                                _Float16* __restrict__ out, int R, int C, int ldo) {
    int idx = blockIdx.x * 256 + threadIdx.x;
    if (idx < R * C) {
        int r = idx / C, c = idx - r * C;
        out[c * ldo + r] = (_Float16)in[idx];
    }
}

// ---- gather-aggregate x: Ah[dst] = fp16( dd*(sum_in dis[s]*x[s] + dd*x[dst]) ) ----
__global__ void k_gather_x(const float* __restrict__ x, const int* __restrict__ row_ptr,
                           const int* __restrict__ csr_src, const float* __restrict__ dis,
                           _Float16* __restrict__ Ah) {
    int dst = blockIdx.x * 4 + (threadIdx.x >> 6);
    if (dst >= NN) return;
    int lane = threadIdx.x & 63;
    float dd = dis[dst];
    const float* xd = x + (size_t)dst * IND + lane * 8;
    float4 a0 = *(const float4*)xd;
    float4 a1 = *(const float4*)(xd + 4);
    float acc[8] = { dd*a0.x, dd*a0.y, dd*a0.z, dd*a0.w,
                     dd*a1.x, dd*a1.y, dd*a1.z, dd*a1.w };
    int beg = row_ptr[dst], end = row_ptr[dst + 1];
    for (int i = beg; i < end; ++i) {
        int s = csr_src[i];
        float ns = dis[s];
        const float* xs = x + (size_t)s * IND + lane * 8;
        float4 b0 = *(const float4*)xs;
        float4 b1 = *(const float4*)(xs + 4);
        acc[0] += ns * b0.x; acc[1] += ns * b0.y; acc[2] += ns * b0.z; acc[3] += ns * b0.w;
        acc[4] += ns * b1.x; acc[5] += ns * b1.y; acc[6] += ns * b1.z; acc[7] += ns * b1.w;
    }
    f16x8 o;
    #pragma unroll
    for (int i = 0; i < 8; ++i) o[i] = (_Float16)(dd * acc[i]);
    *(f16x8*)(Ah + (size_t)dst * IND + lane * 8) = o;
}

// ---- gather-aggregate t + bias + sigmoid -> out (f32) ----
__global__ void k_gather_t(const float* __restrict__ t, const int* __restrict__ row_ptr,
                           const int* __restrict__ csr_src, const float* __restrict__ dis,
                           const float* __restrict__ b2, float* __restrict__ out) {
    int dst = blockIdx.x * 4 + (threadIdx.x >> 6);
    if (dst >= NN) return;
    int lane = threadIdx.x & 63;
    float dd = dis[dst];
    float2 td = *(const float2*)(t + (size_t)dst * LATD + lane * 2);
    float accx = dd * td.x, accy = dd * td.y;
    int beg = row_ptr[dst], end = row_ptr[dst + 1];
    for (int i = beg; i < end; ++i) {
        int s = csr_src[i];
        float ns = dis[s];
        float2 ts = *(const float2*)(t + (size_t)s * LATD + lane * 2);
        accx += ns * ts.x; accy += ns * ts.y;
    }
    float2 bb = *(const float2*)(b2 + lane * 2);
    float vx = dd * accx + bb.x;
    float vy = dd * accy + bb.y;
    float2 o;
    o.x = 1.0f / (1.0f + __expf(-vx));
    o.y = 1.0f / (1.0f + __expf(-vy));
    *(float2*)(out + (size_t)dst * LATD + lane * 2) = o;
}

// ---- MFMA GEMM (m97 structure): C[M][N] = A[M][K] @ Bt[N][K]^T ----
// All dims padded to tile multiples: NO bounds checks anywhere.
// global_load_lds width=16 staging into unpadded LDS [128][32] f16.
template<bool RELU_BIAS>
__global__ __launch_bounds__(256, 2) void k_gemm_lds(
    const _Float16* __restrict__ A,
    const _Float16* __restrict__ Bt,
    const float* __restrict__ bias,   // padded with zeros if RELU_BIAS
    _Float16* __restrict__ Ch,        // fp16 out (ld = N) if RELU_BIAS
    float* __restrict__ Cf,           // f32 out otherwise
    int N, int K)
{
    __shared__ __align__(16) _Float16 As[128 * 32];
    __shared__ __align__(16) _Float16 Bs[128 * 32];

    const int tid = threadIdx.x;
    const int lane = tid & 63;
    const int w = tid >> 6;
    const int mBase = blockIdx.x * 128;
    const int nBase = blockIdx.y * 128;

    // staging: wave w covers tile rows [w*32, w*32+32); lane i -> row w*32 + i/4,
    // cols (i%4)*8..+7 (16 B). LDS dest = chunk*1024B + lane*16B (contiguous, unpadded).
    const int srow = w * 32 + (lane >> 2);
    const int scol = (lane & 3) * 8;
    const _Float16* Ag0 = A + (size_t)(mBase + srow) * K + scol;
    const _Float16* Ag1 = Ag0 + (size_t)16 * K;
    const _Float16* Bg0 = Bt + (size_t)(nBase + srow) * K + scol;
    const _Float16* Bg1 = Bg0 + (size_t)16 * K;
    _Float16* Asl0 = As + w * 1024;   // chunk 2w   (elems; 1024 f16 = 2048 B)
    _Float16* Asl1 = Asl0 + 512;      // chunk 2w+1
    _Float16* Bsl0 = Bs + w * 1024;
    _Float16* Bsl1 = Bsl0 + 512;

    const int wm = (w >> 1) * 64;
    const int wn = (w & 1) * 64;
    const int lm = lane & 15;
    const int quad = lane >> 4;

    f32x4 acc[4][4];
    #pragma unroll
    for (int i = 0; i < 4; ++i)
        #pragma unroll
        for (int j = 0; j < 4; ++j)
            acc[i][j] = (f32x4){0.f, 0.f, 0.f, 0.f};

    for (int k0 = 0; k0 < K; k0 += 32) {
        gload_lds16(Ag0 + k0, Asl0);
        gload_lds16(Ag1 + k0, Asl1);
        gload_lds16(Bg0 + k0, Bsl0);
        gload_lds16(Bg1 + k0, Bsl1);
        __syncthreads();   // drains vmcnt -> tile visible to all waves

        f16x8 af[4], bfr[4];
        #pragma unroll
        for (int mi = 0; mi < 4; ++mi)
            af[mi] = *(const f16x8*)&As[(wm + mi * 16 + lm) * 32 + quad * 8];
        #pragma unroll
        for (int ni = 0; ni < 4; ++ni)
            bfr[ni] = *(const f16x8*)&Bs[(wn + ni * 16 + lm) * 32 + quad * 8];
        #pragma unroll
        for (int mi = 0; mi < 4; ++mi)
            #pragma unroll
            for (int ni = 0; ni < 4; ++ni)
                acc[mi][ni] = __builtin_amdgcn_mfma_f32_16x16x32_f16(
                    af[mi], bfr[ni], acc[mi][ni], 0, 0, 0);
        __syncthreads();   // all reads done before next iter overwrites
    }

    // epilogue; C/D layout: col = lane&15, row = quad*4 + reg
    #pragma unroll
    for (int mi = 0; mi < 4; ++mi) {
        #pragma unroll
        for (int ni = 0; ni < 4; ++ni) {
            int col = nBase + wn + ni * 16 + lm;
            float bval = RELU_BIAS ? bias[col] : 0.f;
            #pragma unroll
            for (int r = 0; r < 4; ++r) {
                int rowg = mBase + wm + mi * 16 + quad * 4 + r;
                float v = acc[mi][ni][r];
                if (RELU_BIAS) {
                    v = fmaxf(v + bval, 0.f);
                    Ch[(size_t)rowg * N + col] = (_Float16)v;
                } else {
                    Cf[(size_t)rowg * N + col] = v;
                }
            }
        }
    }
}

extern "C" void kernel_launch(void* const* d_in, const int* in_sizes, int n_in,
                              void* d_out, int out_size, void* d_ws, size_t ws_size,
                              hipStream_t stream) {
    const float* x  = (const float*)d_in[0];
    const int* ei   = (const int*)d_in[1];
    const float* W1 = (const float*)d_in[2];
    const float* b1 = (const float*)d_in[3];
    const float* W2 = (const float*)d_in[4];
    const float* b2 = (const float*)d_in[5];
    float* out = (float*)d_out;

    char* p = (char*)d_ws;
    auto alloc = [&](size_t bytes) {
        char* q = p; p += (bytes + 255) & ~(size_t)255; return q;
    };
    int* deg        = (int*)alloc((size_t)NN * 4);
    int* row_ptr    = (int*)alloc((size_t)(NN + 1) * 4);
    int* cursor     = (int*)alloc((size_t)NN * 4);
    int* csr_src    = (int*)alloc((size_t)NE * 4);
    float* dis      = (float*)alloc((size_t)NN * 4);
    float* b1pad    = (float*)alloc((size_t)N1_PAD * 4);
    _Float16* W1T   = (_Float16*)alloc((size_t)N1_PAD * IND * 2);   // [2048][512], pad rows zero
    _Float16* W2T   = (_Float16*)alloc((size_t)LATD * N1_PAD * 2);  // [128][2048], pad cols zero
    _Float16* Ah    = (_Float16*)alloc((size_t)M_PAD * IND * 2);    // pad rows: finite garbage, ok
    _Float16* h     = (_Float16*)alloc((size_t)M_PAD * N1_PAD * 2); // pad cols exactly 0
    float* t        = (float*)alloc((size_t)M_PAD * LATD * 4);

    hipMemsetAsync(deg,    0, (size_t)NN * 4, stream);
    hipMemsetAsync(cursor, 0, (size_t)NN * 4, stream);
    hipMemsetAsync(b1pad,  0, (size_t)N1_PAD * 4, stream);
    hipMemsetAsync(W1T,    0, (size_t)N1_PAD * IND * 2, stream);
    hipMemsetAsync(W2T,    0, (size_t)LATD * N1_PAD * 2, stream);
    hipMemcpyAsync(b1pad, b1, (size_t)HIDD * 4, hipMemcpyDeviceToDevice, stream);

    k_degree<<<(NE + 255) / 256, 256, 0, stream>>>(ei + NE, deg);
    k_dis<<<(NN + 255) / 256, 256, 0, stream>>>(deg, dis);
    k_scan<<<1, 1024, 0, stream>>>(deg, row_ptr);
    k_fill<<<(NE + 255) / 256, 256, 0, stream>>>(ei, row_ptr, cursor, csr_src);

    // W1 [512][2000] -> W1T[c][r], ld 512 ; W2 [2000][128] -> W2T[c][r], ld 2048
    k_transpose_cvt<<<(IND * HIDD + 255) / 256, 256, 0, stream>>>(W1, W1T, IND, HIDD, IND);
    k_transpose_cvt<<<(HIDD * LATD + 255) / 256, 256, 0, stream>>>(W2, W2T, HIDD, LATD, N1_PAD);

    k_gather_x<<<(NN + 3) / 4, 256, 0, stream>>>(x, row_ptr, csr_src, dis, Ah);

    dim3 g1(M_PAD / 128, N1_PAD / 128);   // 391 x 16
    k_gemm_lds<true><<<g1, 256, 0, stream>>>(Ah, W1T, b1pad, h, nullptr, N1_PAD, IND);
    dim3 g2(M_PAD / 128, LATD / 128);     // 391 x 1
    k_gemm_lds<false><<<g2, 256, 0, stream>>>(h, W2T, nullptr, nullptr, t, LATD, N1_PAD);

    k_gather_t<<<(NN + 3) / 4, 256, 0, stream>>>(t, row_ptr, csr_src, dis, b2, out);
}

// Round 5
// 597.076 us; speedup vs baseline: 7.1004x; 1.0397x over previous
//
#include <hip/hip_runtime.h>
#include <hip/hip_fp16.h>

#define NN 50000
#define NE 200000
#define IND 512
#define HIDD 2000
#define LATD 128

#define M_PAD 50048    // 391 * 128
#define N1_PAD 2048    // HIDD padded (pad cols forced to exact 0)
#define MT1 391        // M tiles (128)
#define NT1 16         // N tiles (128)
#define SLAB1 49       // ceil(391/8) M-tiles per XCD

typedef _Float16 f16x8 __attribute__((ext_vector_type(8)));
typedef float f32x4 __attribute__((ext_vector_type(4)));

__device__ __forceinline__ void gload_lds16(const _Float16* g, _Float16* l) {
    __builtin_amdgcn_global_load_lds(
        (const __attribute__((address_space(1))) unsigned int*)g,
        (__attribute__((address_space(3))) unsigned int*)l,
        16, 0, 0);
}

// ---- in-degree (int): deg[col[e]] += 1 ----
__global__ void k_degree(const int* __restrict__ col, int* __restrict__ deg) {
    int e = blockIdx.x * 256 + threadIdx.x;
    if (e < NE) atomicAdd(&deg[col[e]], 1);
}

// ---- dis = rsqrt(deg + 1 self-loop) ----
__global__ void k_dis(const int* __restrict__ deg, float* __restrict__ dis) {
    int i = blockIdx.x * 256 + threadIdx.x;
    if (i < NN) dis[i] = rsqrtf((float)deg[i] + 1.0f);
}

// ---- exclusive prefix scan of deg -> row_ptr (single 1024-thread block) ----
__global__ void k_scan(const int* __restrict__ deg, int* __restrict__ row_ptr) {
    __shared__ int smem[1024];
    const int tid = threadIdx.x;
    int carry = 0;
    for (int chunk = 0; chunk < NN; chunk += 1024) {
        int i = chunk + tid;
        int v = (i < NN) ? deg[i] : 0;
        smem[tid] = v;
        __syncthreads();
        #pragma unroll
        for (int off = 1; off < 1024; off <<= 1) {
            int t = (tid >= off) ? smem[tid - off] : 0;
            __syncthreads();
            if (tid >= off) smem[tid] += t;
            __syncthreads();
        }
        if (i < NN) row_ptr[i] = carry + smem[tid] - v;   // exclusive
        int tot = smem[1023];
        __syncthreads();
        carry += tot;
    }
    if (tid == 0) row_ptr[NN] = carry;
}

// ---- fill CSR: csr_src[row_ptr[c] + cursor[c]++] = r ----
__global__ void k_fill(const int* __restrict__ ei, const int* __restrict__ row_ptr,
                       int* __restrict__ cursor, int* __restrict__ csr_src) {
    int e = blockIdx.x * 256 + threadIdx.x;
    if (e < NE) {
        int r = ei[e], c = ei[NE + e];
        int pos = atomicAdd(&cursor[c], 1);
        csr_src[row_ptr[c] + pos] = r;
    }
}

// ---- LDS-tiled transpose+convert: in f32 [R][C] -> out fp16, out[c*ldo + r] ----
__global__ void k_transpose_tiled(const float* __restrict__ in,
                                  _Float16* __restrict__ out, int R, int C, int ldo) {
    __shared__ float sm[32][33];
    int c0 = blockIdx.x * 32, r0 = blockIdx.y * 32;
    int tx = threadIdx.x & 31, ty = threadIdx.x >> 5;   // 32 x 8
    #pragma unroll
    for (int i = 0; i < 4; ++i) {
        int r = r0 + ty + i * 8, c = c0 + tx;
        sm[ty + i * 8][tx] = (r < R && c < C) ? in[(size_t)r * C + c] : 0.f;
    }
    __syncthreads();
    #pragma unroll
    for (int i = 0; i < 4; ++i) {
        int c = c0 + ty + i * 8, r = r0 + tx;
        if (c < C && r < R) out[(size_t)c * ldo + r] = (_Float16)sm[tx][ty + i * 8];
    }
}

// ---- gather-aggregate x: Ah[dst] = fp16( dd*(sum_in dis[s]*x[s] + dd*x[dst]) ) ----
__global__ void k_gather_x(const float* __restrict__ x, const int* __restrict__ row_ptr,
                           const int* __restrict__ csr_src, const float* __restrict__ dis,
                           _Float16* __restrict__ Ah) {
    int dst = blockIdx.x * 4 + (threadIdx.x >> 6);
    if (dst >= NN) return;
    int lane = threadIdx.x & 63;
    float dd = dis[dst];
    const float* xd = x + (size_t)dst * IND + lane * 8;
    float4 a0 = *(const float4*)xd;
    float4 a1 = *(const float4*)(xd + 4);
    float acc[8] = { dd*a0.x, dd*a0.y, dd*a0.z, dd*a0.w,
                     dd*a1.x, dd*a1.y, dd*a1.z, dd*a1.w };
    int beg = row_ptr[dst], end = row_ptr[dst + 1];
    for (int i = beg; i < end; ++i) {
        int s = csr_src[i];
        float ns = dis[s];
        const float* xs = x + (size_t)s * IND + lane * 8;
        float4 b0 = *(const float4*)xs;
        float4 b1 = *(const float4*)(xs + 4);
        acc[0] += ns * b0.x; acc[1] += ns * b0.y; acc[2] += ns * b0.z; acc[3] += ns * b0.w;
        acc[4] += ns * b1.x; acc[5] += ns * b1.y; acc[6] += ns * b1.z; acc[7] += ns * b1.w;
    }
    f16x8 o;
    #pragma unroll
    for (int i = 0; i < 8; ++i) o[i] = (_Float16)(dd * acc[i]);
    *(f16x8*)(Ah + (size_t)dst * IND + lane * 8) = o;
}

// ---- gather-aggregate t + bias + sigmoid -> out (f32) ----
__global__ void k_gather_t(const float* __restrict__ t, const int* __restrict__ row_ptr,
                           const int* __restrict__ csr_src, const float* __restrict__ dis,
                           const float* __restrict__ b2, float* __restrict__ out) {
    int dst = blockIdx.x * 4 + (threadIdx.x >> 6);
    if (dst >= NN) return;
    int lane = threadIdx.x & 63;
    float dd = dis[dst];
    float2 td = *(const float2*)(t + (size_t)dst * LATD + lane * 2);
    float accx = dd * td.x, accy = dd * td.y;
    int beg = row_ptr[dst], end = row_ptr[dst + 1];
    for (int i = beg; i < end; ++i) {
        int s = csr_src[i];
        float ns = dis[s];
        float2 ts = *(const float2*)(t + (size_t)s * LATD + lane * 2);
        accx += ns * ts.x; accy += ns * ts.y;
    }
    float2 bb = *(const float2*)(b2 + lane * 2);
    float vx = dd * accx + bb.x;
    float vy = dd * accy + bb.y;
    float2 o;
    o.x = 1.0f / (1.0f + __expf(-vx));
    o.y = 1.0f / (1.0f + __expf(-vy));
    *(float2*)(out + (size_t)dst * LATD + lane * 2) = o;
}

// ---- GEMM1: h = relu(Ah @ W1T^T + b1), 128x128 tile, XCD-slab swizzled 1D grid ----
// grid = 8 * SLAB1 * NT1 blocks; xcd = b&7 gets M-slab [xcd*SLAB1, ...), N-fastest.
__global__ __launch_bounds__(256, 2) void k_gemm1(
    const _Float16* __restrict__ A,    // [M_PAD][512]
    const _Float16* __restrict__ Bt,   // [2048][512]
    const float* __restrict__ bias,    // [2048] (pad zeros)
    _Float16* __restrict__ Ch)         // [M_PAD][2048]
{
    const int b = blockIdx.x;
    const int mT = (b & 7) * SLAB1 + ((b >> 3) >> 4);
    const int nT = (b >> 3) & 15;
    if (mT >= MT1) return;
    const int mBase = mT * 128;
    const int nBase = nT * 128;

    __shared__ __align__(16) _Float16 As[128 * 32];
    __shared__ __align__(16) _Float16 Bs[128 * 32];

    const int tid = threadIdx.x;
    const int lane = tid & 63;
    const int w = tid >> 6;

    const int srow = w * 32 + (lane >> 2);
    const int scol = (lane & 3) * 8;
    const _Float16* Ag0 = A + (size_t)(mBase + srow) * IND + scol;
    const _Float16* Ag1 = Ag0 + (size_t)16 * IND;
    const _Float16* Bg0 = Bt + (size_t)(nBase + srow) * IND + scol;
    const _Float16* Bg1 = Bg0 + (size_t)16 * IND;
    _Float16* Asl0 = As + w * 1024;
    _Float16* Asl1 = Asl0 + 512;
    _Float16* Bsl0 = Bs + w * 1024;
    _Float16* Bsl1 = Bsl0 + 512;

    const int wm = (w >> 1) * 64;
    const int wn = (w & 1) * 64;
    const int lm = lane & 15;
    const int quad = lane >> 4;

    f32x4 acc[4][4];
    #pragma unroll
    for (int i = 0; i < 4; ++i)
        #pragma unroll
        for (int j = 0; j < 4; ++j)
            acc[i][j] = (f32x4){0.f, 0.f, 0.f, 0.f};

    for (int k0 = 0; k0 < IND; k0 += 32) {
        gload_lds16(Ag0 + k0, Asl0);
        gload_lds16(Ag1 + k0, Asl1);
        gload_lds16(Bg0 + k0, Bsl0);
        gload_lds16(Bg1 + k0, Bsl1);
        __syncthreads();

        f16x8 af[4], bfr[4];
        #pragma unroll
        for (int mi = 0; mi < 4; ++mi)
            af[mi] = *(const f16x8*)&As[(wm + mi * 16 + lm) * 32 + quad * 8];
        #pragma unroll
        for (int ni = 0; ni < 4; ++ni)
            bfr[ni] = *(const f16x8*)&Bs[(wn + ni * 16 + lm) * 32 + quad * 8];
        #pragma unroll
        for (int mi = 0; mi < 4; ++mi)
            #pragma unroll
            for (int ni = 0; ni < 4; ++ni)
                acc[mi][ni] = __builtin_amdgcn_mfma_f32_16x16x32_f16(
                    af[mi], bfr[ni], acc[mi][ni], 0, 0, 0);
        __syncthreads();
    }

    #pragma unroll
    for (int mi = 0; mi < 4; ++mi) {
        #pragma unroll
        for (int ni = 0; ni < 4; ++ni) {
            int col = nBase + wn + ni * 16 + lm;
            float bval = bias[col];
            #pragma unroll
            for (int r = 0; r < 4; ++r) {
                int rowg = mBase + wm + mi * 16 + quad * 4 + r;
                float v = fmaxf(acc[mi][ni][r] + bval, 0.f);
                Ch[(size_t)rowg * N1_PAD + col] = (_Float16)v;
            }
        }
    }
}

// ---- GEMM2: t = h @ W2T^T, 64x128 tile (782 blocks for occupancy), f32 out ----
__global__ __launch_bounds__(256, 2) void k_gemm2(
    const _Float16* __restrict__ A,    // [M_PAD][2048]
    const _Float16* __restrict__ Bt,   // [128][2048]
    float* __restrict__ Cf)            // [M_PAD][128]
{
    __shared__ __align__(16) _Float16 As[64 * 32];    // 4 KB
    __shared__ __align__(16) _Float16 Bs[128 * 32];   // 8 KB

    const int tid = threadIdx.x;
    const int lane = tid & 63;
    const int w = tid >> 6;
    const int mBase = blockIdx.x * 64;

    const int srA = w * 16 + (lane >> 2);
    const int srB = w * 32 + (lane >> 2);
    const int scol = (lane & 3) * 8;
    const _Float16* Ag  = A + (size_t)(mBase + srA) * N1_PAD + scol;
    const _Float16* Bg0 = Bt + (size_t)srB * N1_PAD + scol;
    const _Float16* Bg1 = Bg0 + (size_t)16 * N1_PAD;
    _Float16* Asl  = As + w * 512;
    _Float16* Bsl0 = Bs + w * 1024;
    _Float16* Bsl1 = Bsl0 + 512;

    const int wm = (w & 1) * 32;
    const int wn = (w >> 1) * 64;
    const int lm = lane & 15;
    const int quad = lane >> 4;

    f32x4 acc[2][4];
    #pragma unroll
    for (int i = 0; i < 2; ++i)
        #pragma unroll
        for (int j = 0; j < 4; ++j)
            acc[i][j] = (f32x4){0.f, 0.f, 0.f, 0.f};

    for (int k0 = 0; k0 < N1_PAD; k0 += 32) {
        gload_lds16(Ag + k0, Asl);
        gload_lds16(Bg0 + k0, Bsl0);
        gload_lds16(Bg1 + k0, Bsl1);
        __syncthreads();

        f16x8 af[2], bfr[4];
        #pragma unroll
        for (int mi = 0; mi < 2; ++mi)
            af[mi] = *(const f16x8*)&As[(wm + mi * 16 + lm) * 32 + quad * 8];
        #pragma unroll
        for (int ni = 0; ni < 4; ++ni)
            bfr[ni] = *(const f16x8*)&Bs[(wn + ni * 16 + lm) * 32 + quad * 8];
        #pragma unroll
        for (int mi = 0; mi < 2; ++mi)
            #pragma unroll
            for (int ni = 0; ni < 4; ++ni)
                acc[mi][ni] = __builtin_amdgcn_mfma_f32_16x16x32_f16(
                    af[mi], bfr[ni], acc[mi][ni], 0, 0, 0);
        __syncthreads();
    }

    #pragma unroll
    for (int mi = 0; mi < 2; ++mi) {
        #pragma unroll
        for (int ni = 0; ni < 4; ++ni) {
            int col = wn + ni * 16 + lm;
            #pragma unroll
            for (int r = 0; r < 4; ++r) {
                int rowg = mBase + wm + mi * 16 + quad * 4 + r;
                Cf[(size_t)rowg * LATD + col] = acc[mi][ni][r];
            }
        }
    }
}

extern "C" void kernel_launch(void* const* d_in, const int* in_sizes, int n_in,
                              void* d_out, int out_size, void* d_ws, size_t ws_size,
                              hipStream_t stream) {
    const float* x  = (const float*)d_in[0];
    const int* ei   = (const int*)d_in[1];
    const float* W1 = (const float*)d_in[2];
    const float* b1 = (const float*)d_in[3];
    const float* W2 = (const float*)d_in[4];
    const float* b2 = (const float*)d_in[5];
    float* out = (float*)d_out;

    char* p = (char*)d_ws;
    auto alloc = [&](size_t bytes) {
        char* q = p; p += (bytes + 255) & ~(size_t)255; return q;
    };
    int* deg        = (int*)alloc((size_t)NN * 4);
    int* row_ptr    = (int*)alloc((size_t)(NN + 1) * 4);
    int* cursor     = (int*)alloc((size_t)NN * 4);
    int* csr_src    = (int*)alloc((size_t)NE * 4);
    float* dis      = (float*)alloc((size_t)NN * 4);
    float* b1pad    = (float*)alloc((size_t)N1_PAD * 4);
    _Float16* W1T   = (_Float16*)alloc((size_t)N1_PAD * IND * 2);   // [2048][512]
    _Float16* W2T   = (_Float16*)alloc((size_t)LATD * N1_PAD * 2);  // [128][2048]
    _Float16* Ah    = (_Float16*)alloc((size_t)M_PAD * IND * 2);
    _Float16* h     = (_Float16*)alloc((size_t)M_PAD * N1_PAD * 2);
    float* t        = (float*)alloc((size_t)M_PAD * LATD * 4);

    hipMemsetAsync(deg,    0, (size_t)NN * 4, stream);
    hipMemsetAsync(cursor, 0, (size_t)NN * 4, stream);
    hipMemsetAsync(b1pad,  0, (size_t)N1_PAD * 4, stream);
    hipMemsetAsync(W1T,    0, (size_t)N1_PAD * IND * 2, stream);
    hipMemsetAsync(W2T,    0, (size_t)LATD * N1_PAD * 2, stream);
    hipMemcpyAsync(b1pad, b1, (size_t)HIDD * 4, hipMemcpyDeviceToDevice, stream);

    k_degree<<<(NE + 255) / 256, 256, 0, stream>>>(ei + NE, deg);
    k_dis<<<(NN + 255) / 256, 256, 0, stream>>>(deg, dis);
    k_scan<<<1, 1024, 0, stream>>>(deg, row_ptr);
    k_fill<<<(NE + 255) / 256, 256, 0, stream>>>(ei, row_ptr, cursor, csr_src);

    // W1 [512][2000] -> W1T[c][r] ld 512 ; W2 [2000][128] -> W2T[c][r] ld 2048
    {
        dim3 gt1((HIDD + 31) / 32, (IND + 31) / 32);
        k_transpose_tiled<<<gt1, 256, 0, stream>>>(W1, W1T, IND, HIDD, IND);
        dim3 gt2((LATD + 31) / 32, (HIDD + 31) / 32);
        k_transpose_tiled<<<gt2, 256, 0, stream>>>(W2, W2T, HIDD, LATD, N1_PAD);
    }

    k_gather_x<<<(NN + 3) / 4, 256, 0, stream>>>(x, row_ptr, csr_src, dis, Ah);

    k_gemm1<<<8 * SLAB1 * NT1, 256, 0, stream>>>(Ah, W1T, b1pad, h);
    k_gemm2<<<M_PAD / 64, 256, 0, stream>>>(h, W2T, t);

    k_gather_t<<<(NN + 3) / 4, 256, 0, stream>>>(t, row_ptr, csr_src, dis, b2, out);
}